// Round 7
// baseline (404.795 us; speedup 1.0000x reference)
//
#include <hip/hip_runtime.h>

// B=8192, NOBJ=1024; inputs [B,NOBJ,2,3] f32; only row 1 (euler) used.
// loss = sum over pairs of acos(clip(0.5*(trace(Rs*Rt^T)-1))) / B
//
// Evidence so far: kernel is bound by the beyond-L2 memory path (~3 TB/s
// effective); VALU and access-pattern changes are all null. Theory: the
// harness's 384MiB d_in restore leaves L3 full of dirty lines; our read
// misses allocate into L3 and force writebacks of not-yet-read dirty lines
// (thrash). Fix attempt: NON-TEMPORAL loads (no allocation on miss,
// still hit resident lines) -> pure-read HBM stream, no writeback storm.
//
// NOTE: __builtin_nontemporal_load requires a clang native vector type,
// not HIP_vector_type<float,4> — use ext_vector_type(4).
typedef float f32x4 __attribute__((ext_vector_type(4)));

#define NPAIRS (8192u * 1024u)   // 8,388,608
#define BLOCK  256
#define GRID   2048
#define NTHREADS (GRID * BLOCK)  // 524,288 -> exactly 8 chunks/thread
#define EPSF   1e-6f

// trace(R(e0) R(e1)^T) via angle differences (algebraically reduced,
// verified vs full matrix form):
//   trace = cp0*cp1*(cos(dr)+cos(dy)) + sp0*sp1
//         + (1 + sp0*sp1)*cos(dr)*cos(dy) + (sp0+sp1)*sin(dr)*sin(dy)
__device__ __forceinline__ float pair_loss(float r0, float p0, float y0,
                                           float r1, float p1, float y1) {
    float sp0 = __sinf(p0), cp0 = __cosf(p0);
    float sp1 = __sinf(p1), cp1 = __cosf(p1);
    float dr = r1 - r0, dy = y1 - y0;
    float sdr = __sinf(dr), cdr = __cosf(dr);
    float sdy = __sinf(dy), cdy = __cosf(dy);

    float m2 = sp0 * sp1;
    float cc = cdr * cdy;
    float tr = cp0 * cp1 * (cdr + cdy);
    tr += m2;
    tr += fmaf(m2, cc, cc);                    // (1 + sp0*sp1)*cc
    tr = fmaf(sp0 + sp1, sdr * sdy, tr);

    float theta = fmaf(0.5f, tr, -0.5f);
    theta = fminf(fmaxf(theta, -1.0f + EPSF), 1.0f - EPSF);
    return acosf(theta);
}

// Chunk = 2 consecutive pairs = 12 floats = 3 f32x4 per tensor.
// Chunk layout: [t0 t1 t2 | e0 e1 e2 | T0 T1 T2 | E0 E1 E2]
//   pair A euler = f0.w,f1.x,f1.y ; pair B euler = f2.y,f2.z,f2.w
// Exactly 8 chunks per thread; fully unrolled with a 1-deep double buffer
// (all buffer indices constant after unroll -> stays in VGPRs).
__global__ __launch_bounds__(BLOCK) void rot_loss_partial(
    const f32x4* __restrict__ outp, const f32x4* __restrict__ targ,
    float* __restrict__ partial) {
    const unsigned tid = blockIdx.x * BLOCK + threadIdx.x;

    f32x4 bo[2][3], bt[2][3];
    float acc = 0.0f;

    {
        const unsigned b = 3u * tid;
        #pragma unroll
        for (int j = 0; j < 3; ++j) {
            bo[0][j] = __builtin_nontemporal_load(&outp[b + j]);
            bt[0][j] = __builtin_nontemporal_load(&targ[b + j]);
        }
    }

    #pragma unroll
    for (unsigned k = 0; k < 8; ++k) {
        const unsigned cur = k & 1u, nxt = cur ^ 1u;
        if (k < 7) {
            const unsigned nb = 3u * (tid + (k + 1) * NTHREADS);
            #pragma unroll
            for (int j = 0; j < 3; ++j) {
                bo[nxt][j] = __builtin_nontemporal_load(&outp[nb + j]);
                bt[nxt][j] = __builtin_nontemporal_load(&targ[nb + j]);
            }
        }
        acc += pair_loss(bo[cur][0].w, bo[cur][1].x, bo[cur][1].y,
                         bt[cur][0].w, bt[cur][1].x, bt[cur][1].y);
        acc += pair_loss(bo[cur][2].y, bo[cur][2].z, bo[cur][2].w,
                         bt[cur][2].y, bt[cur][2].z, bt[cur][2].w);
    }

    // wave-64 shuffle reduce
    #pragma unroll
    for (int off = 32; off > 0; off >>= 1) acc += __shfl_down(acc, off);

    __shared__ float ws[BLOCK / 64];
    const int lane = threadIdx.x & 63;
    const int wave = threadIdx.x >> 6;
    if (lane == 0) ws[wave] = acc;
    __syncthreads();
    if (threadIdx.x == 0) {
        float s = 0.0f;
        #pragma unroll
        for (int w = 0; w < BLOCK / 64; ++w) s += ws[w];
        partial[blockIdx.x] = s;  // written unconditionally (d_ws is poisoned)
    }
}

__global__ __launch_bounds__(BLOCK) void rot_loss_final(
    const float* __restrict__ partial, float* __restrict__ out) {
    double acc = 0.0;
    for (int i = threadIdx.x; i < GRID; i += BLOCK) acc += (double)partial[i];
    #pragma unroll
    for (int off = 32; off > 0; off >>= 1) acc += __shfl_down(acc, off);
    __shared__ double ws[BLOCK / 64];
    const int lane = threadIdx.x & 63;
    const int wave = threadIdx.x >> 6;
    if (lane == 0) ws[wave] = acc;
    __syncthreads();
    if (threadIdx.x == 0) {
        double s = 0.0;
        #pragma unroll
        for (int w = 0; w < BLOCK / 64; ++w) s += ws[w];
        out[0] = (float)(s / 8192.0);
    }
}

extern "C" void kernel_launch(void* const* d_in, const int* in_sizes, int n_in,
                              void* d_out, int out_size, void* d_ws, size_t ws_size,
                              hipStream_t stream) {
    const f32x4* outp = (const f32x4*)d_in[0];
    const f32x4* targ = (const f32x4*)d_in[1];
    float* partial = (float*)d_ws;  // GRID floats = 8 KiB
    float* out = (float*)d_out;

    rot_loss_partial<<<GRID, BLOCK, 0, stream>>>(outp, targ, partial);
    rot_loss_final<<<1, BLOCK, 0, stream>>>(partial, out);
}